// Round 11
// baseline (54.683 us; speedup 1.0000x reference)
//
#include <hip/hip_runtime.h>

#define BB 32
#define CC 1024
#define QQ 128
#define EE 512

typedef unsigned int uint32;
typedef unsigned short u16;
typedef __bf16 bf16x8 __attribute__((ext_vector_type(8)));
typedef float f32x4 __attribute__((ext_vector_type(4)));

// workspace layout (bytes), total ~21MB
#define QMF_OFF  (0u)                        // bf16 frag-major: [b][ks16][nf8][lane][8] (qm' = q*ws_m + ws_c)
#define QTF_OFF  (4u<<20)                    // bf16 frag-major: [b][ks2 4][ne32][lane][8]
#define QDP_OFF  (8u<<20)                    // f32 [b][et4][128] qdot partials (64KB)
#define RDEN_OFF ((8u<<20)+(64u<<10))        // f32 [b][1024] softmax 1/denominator (128KB)
#define MB_OFF   ((8u<<20)+(192u<<10))       // f32 [b][64] tile max (8KB)
#define SB_OFF   ((8u<<20)+(200u<<10))       // f32 [b][64] tile expsum (8KB)
#define PVB_OFF  ((8u<<20)+(256u<<10))       // f32 [b][64][512] q2c partial (4MB)
#define P_OFF    (13u<<20)                   // bf16 P frags: [b][g64][ks2 4][lane][8] (8MB)

__device__ __forceinline__ u16 bfc(float f){
  __bf16 h = (__bf16)f;                // HW v_cvt (RNE)
  return __builtin_bit_cast(u16, h);
}
__device__ __forceinline__ float bf2f(uint32 lo16){
  return __builtin_bit_cast(float, lo16 << 16);
}

// ---- fused prep: per (b, e-slice et): qm' frags + qt frags + qdot partial ----
__global__ __launch_bounds__(256) void k_prep(const float* __restrict__ q,
                                              const float* __restrict__ ws,
                                              unsigned char* __restrict__ wsp){
  const int b = blockIdx.x >> 2, et = blockIdx.x & 3, e0 = et*128;
  __shared__ u16 tm[128*136];          // qm' = q*ws_m + ws_c (bf16)
  __shared__ u16 tt[128*136];          // raw q (bf16)
  const int tid = threadIdx.x;
  float* qdp = (float*)(wsp + QDP_OFF) + (size_t)(b*4 + et)*128;
  #pragma unroll
  for (int i=0;i<16;i++){
    int id = tid + i*256;
    int qi = id >> 5;
    int el = (id & 31) << 2;
    float4 v = *(const float4*)(q + (size_t)(b*QQ+qi)*EE + e0 + el);
    float4 a = *(const float4*)(ws +          e0 + el);
    float4 c = *(const float4*)(ws +   EE +   e0 + el);
    float4 m = *(const float4*)(ws + 2*EE +   e0 + el);
    ushort4 um; um.x = bfc(v.x*m.x + c.x); um.y = bfc(v.y*m.y + c.y);
                um.z = bfc(v.z*m.z + c.z); um.w = bfc(v.w*m.w + c.w);
    *(ushort4*)&tm[qi*136 + el] = um;
    ushort4 ut; ut.x = bfc(v.x); ut.y = bfc(v.y); ut.z = bfc(v.z); ut.w = bfc(v.w);
    *(ushort4*)&tt[qi*136 + el] = ut;
    float d = v.x*a.x + v.y*a.y + v.z*a.z + v.w*a.w;
    d += __shfl_xor(d,1); d += __shfl_xor(d,2); d += __shfl_xor(d,4);
    d += __shfl_xor(d,8); d += __shfl_xor(d,16);
    if ((tid & 31) == 0) qdp[qi] = d;
  }
  __syncthreads();
  const int lane = tid & 63, wv = tid >> 6, l15 = lane & 15, l4 = lane >> 4;
  uint4* qmf = (uint4*)(wsp + QMF_OFF);
  uint4* qtf = (uint4*)(wsp + QTF_OFF);
  #pragma unroll
  for (int i=0;i<8;i++){
    int f = wv*8 + i;
    int kl = f >> 3, nf = f & 7;
    uint4 u = *(const uint4*)&tm[(nf*16 + l15)*136 + kl*32 + l4*8];
    qmf[(size_t)((b*16 + et*4 + kl)*8 + nf)*64 + lane] = u;
  }
  #pragma unroll
  for (int i=0;i<8;i++){
    int f = wv*8 + i;
    int ks2 = f >> 3, nl = f & 7, ne = et*8 + nl;
    uint32 x[4];
    #pragma unroll
    for (int p=0;p<4;p++){
      u16 t0 = tt[(ks2*32 + l4*8 + 2*p    )*136 + nl*16 + l15];
      u16 t1 = tt[(ks2*32 + l4*8 + 2*p + 1)*136 + nl*16 + l15];
      x[p] = (uint32)t0 | ((uint32)t1 << 16);
    }
    uint4 u; u.x = x[0]; u.y = x[1]; u.z = x[2]; u.w = x[3];
    qtf[(size_t)((b*4 + ks2)*32 + ne)*64 + lane] = u;
  }
}

// ---- k_sim: READ-bound. 2048 blocks (b x 16-row tile) x 8 waves = 8 rounds/CU.
// ctx tile -> LDS bf16; flipped GEMM1 (qm' regs x ctx LDS); m=0 softmax;
// P bf16 frags -> workspace (L3); rden, q2c tile stats + PV partial.
__global__ __launch_bounds__(512, 4) void k_sim(const float* __restrict__ ctx,
                                                unsigned char* __restrict__ wsp){
  __shared__ __align__(16) unsigned char buf[16384]; // ctx bf16 [16][512] XOR-swz
  __shared__ float mx_s[16*8];
  __shared__ float sm_s[16*8];
  __shared__ float wrow_s[16];

  const int bid = blockIdx.x;
  const int sw  = (bid & 7)*256 + (bid >> 3);  // XCD-contiguous (2048%8==0)
  const int b   = sw >> 6;
  const int t   = sw & 63;                     // 16-row tile
  const int tid = threadIdx.x;
  const int lane = tid & 63;
  const int w    = tid >> 6;                   // q-16-group
  const int l15  = lane & 15;
  const int l4   = lane >> 4;

  // ctx tile loads first (HBM long-pole): 16 rows x 512 f32 = 32KB
  const float4* cb4 = (const float4*)(ctx + (size_t)(b*CC + t*16)*EE);
  float4 v[4];
  #pragma unroll
  for (int i=0;i<4;i++) v[i] = cb4[i*512 + tid];

  // qdot (L2-hot, small)
  float qdv[4];
  {
    const float* qdp = (const float*)(wsp + QDP_OFF) + (size_t)b*512;
    #pragma unroll
    for (int r=0;r<4;r++){
      const int qi = w*16 + l4*4 + r;
      qdv[r] = qdp[qi] + qdp[128+qi] + qdp[256+qi] + qdp[384+qi];
    }
  }

  // stage: cvt + ds_write (XOR-swz 16B slots)
  {
    const int colb = (tid & 127)*8;
    #pragma unroll
    for (int i=0;i<4;i++){
      const int row = i*4 + (tid >> 7);
      uint2 u;
      u.x = (uint32)bfc(v[i].x) | ((uint32)bfc(v[i].y) << 16);
      u.y = (uint32)bfc(v[i].z) | ((uint32)bfc(v[i].w) << 16);
      *(uint2*)(buf + row*1024 + (colb ^ ((row & 7) << 4))) = u;
    }
  }
  __syncthreads();                             // buf ready

  // qm' A-frags loaded AFTER the barrier (L2-hot; keeps staging-phase VGPR low)
  const uint4* qmf4 = (const uint4*)(wsp + QMF_OFF);
  f32x4 acc = (f32x4){0.f,0.f,0.f,0.f};
  #pragma unroll
  for (int ks=0; ks<16; ks++){
    bf16x8 a = __builtin_bit_cast(bf16x8, qmf4[(size_t)((b*16 + ks)*8 + w)*64 + lane]);
    bf16x8 bf = __builtin_bit_cast(bf16x8,
      *(const uint4*)(buf + l15*1024 + ((ks*64 + l4*16) ^ ((l15 & 7) << 4))));
    acc = __builtin_amdgcn_mfma_f32_16x16x32_bf16(a, bf, acc, 0, 0, 0);
  }

  // softmax (m=0 exp, shift-invariant, clamp 80): P frag -> global, stats -> LDS
  {
    float m = -3.0e38f, s = 0.f;
    u16 hb[4];
    #pragma unroll
    for (int r=0;r<4;r++){
      float vv = fminf(acc[r] + qdv[r], 80.f);
      m = fmaxf(m, vv);
      u16 h = bfc(__expf(vv));
      hb[r] = h;
      s += bf2f(h);
    }
    uint2 u; u.x = (uint32)hb[0] | ((uint32)hb[1]<<16);
             u.y = (uint32)hb[2] | ((uint32)hb[3]<<16);
    *(uint2*)(wsp + P_OFF
      + ((size_t)(b*64 + t)*4 + (w>>1))*1024
      + (((2*w + (l4>>1)) & 3)*16 + l15)*16 + (l4&1)*8) = u;
    m = fmaxf(m, __shfl_xor(m, 16)); m = fmaxf(m, __shfl_xor(m, 32));
    s += __shfl_xor(s, 16);          s += __shfl_xor(s, 32);
    if (l4 == 0){ mx_s[l15*8 + w] = m; sm_s[l15*8 + w] = s; }
  }
  __syncthreads();                             // stats visible

  // rden + q2c tile stats (lanes 0..15 of wave 0)
  if (tid < 16){
    const float* sp = &sm_s[tid*8];
    float sum = sp[0]+sp[1]+sp[2]+sp[3]+sp[4]+sp[5]+sp[6]+sp[7];
    ((float*)(wsp + RDEN_OFF))[b*1024 + t*16 + tid] = 1.f/sum;
    const float* mp = &mx_s[tid*8];
    float mf = fmaxf(fmaxf(fmaxf(mp[0],mp[1]),fmaxf(mp[2],mp[3])),
                     fmaxf(fmaxf(mp[4],mp[5]),fmaxf(mp[6],mp[7])));
    float M = mf;
    M = fmaxf(M, __shfl_xor(M,1)); M = fmaxf(M, __shfl_xor(M,2));
    M = fmaxf(M, __shfl_xor(M,4)); M = fmaxf(M, __shfl_xor(M,8));
    float wr = __expf(mf - M);
    wrow_s[tid] = wr;
    float S = wr;
    S += __shfl_xor(S,1); S += __shfl_xor(S,2);
    S += __shfl_xor(S,4); S += __shfl_xor(S,8);
    if (tid == 0){
      ((float*)(wsp + MB_OFF))[b*64 + t] = M;
      ((float*)(wsp + SB_OFF))[b*64 + t] = S;
    }
  }
  __syncthreads();                             // wrow visible

  // q2c PV partial from LDS bf16 ctx (thread owns e=tid)
  {
    float pv = 0.f;
    #pragma unroll
    for (int rr=0; rr<16; rr++){
      uint32 x = *(const u16*)(buf + rr*1024 + ((tid*2) ^ ((rr & 7) << 4)));
      pv = fmaf(wrow_s[rr], bf2f(x), pv);
    }
    ((float*)(wsp + PVB_OFF))[(size_t)(b*64 + t)*512 + tid] = pv;
  }
}

// ---- k_out: WRITE-bound. 2048 blocks (b x 64-row x 128-e tile) x 4 waves,
// plus 32 fin-blocks (q2c combine; depends only on k_sim).
__global__ __launch_bounds__(256, 4) void k_out(unsigned char* __restrict__ wsp,
                                                float* __restrict__ out){
  __shared__ __align__(16) unsigned char qts[32768]; // qtf slice [ks2 4][ne 8][1KB]
  __shared__ float sc_s[64];
  __shared__ float dinv_s;

  const int bid = blockIdx.x;
  const int tid = threadIdx.x;

  if (bid >= 2048){
    // ---- q2c combine for batch b: 64 tile-partials ----
    const int b = bid - 2048;
    if (tid < 64){
      float Mk = ((const float*)(wsp + MB_OFF))[b*64 + tid];
      float Sk = ((const float*)(wsp + SB_OFF))[b*64 + tid];
      float M = Mk;
      M = fmaxf(M, __shfl_xor(M,1));  M = fmaxf(M, __shfl_xor(M,2));
      M = fmaxf(M, __shfl_xor(M,4));  M = fmaxf(M, __shfl_xor(M,8));
      M = fmaxf(M, __shfl_xor(M,16)); M = fmaxf(M, __shfl_xor(M,32));
      float ev = __expf(Mk - M);
      float d = ev*Sk;
      d += __shfl_xor(d,1);  d += __shfl_xor(d,2);  d += __shfl_xor(d,4);
      d += __shfl_xor(d,8);  d += __shfl_xor(d,16); d += __shfl_xor(d,32);
      sc_s[tid] = ev;
      if (tid == 0) dinv_s = 1.f/d;
    }
    __syncthreads();
    const float* pvb = (const float*)(wsp + PVB_OFF) + (size_t)b*64*512;
    float a0 = 0.f, a1 = 0.f;
    #pragma unroll 8
    for (int k=0;k<64;k++){
      float s = sc_s[k];
      a0 = fmaf(s, pvb[(size_t)k*512 + tid],       a0);
      a1 = fmaf(s, pvb[(size_t)k*512 + tid + 256], a1);
    }
    size_t base = (size_t)BB*CC*EE + (size_t)b*EE;
    float di = dinv_s;
    out[base + tid]       = a0*di;
    out[base + tid + 256] = a1*di;
    return;
  }

  const int sw  = (bid & 7)*256 + (bid >> 3);  // XCD-contiguous (2048%8==0)
  const int b   = sw >> 6;
  const int rr  = sw & 63;
  const int ct  = rr >> 2;                     // 64-row tile (0..15)
  const int et  = rr & 3;                      // 128-e tile
  const int lane = tid & 63;
  const int w    = tid >> 6;                   // c-16-group within tile
  const int l15  = lane & 15;
  const int l4   = lane >> 4;

  // DMA qtf slice: wave w loads ks2=w's 8 ne-frags (8KB)
  const unsigned char* qtfb = wsp + QTF_OFF + (size_t)b*131072;
  #pragma unroll
  for (int j=0;j<8;j++){
    __builtin_amdgcn_global_load_lds(
      (const __attribute__((address_space(1))) uint32*)
        (qtfb + (size_t)(w*32 + et*8 + j)*1024 + lane*16),
      (__attribute__((address_space(3))) uint32*)(qts + (w*8 + j)*1024), 16, 0, 0);
  }

  // P A-frags (L3-hot) + rden
  bf16x8 pa[4];
  #pragma unroll
  for (int k2=0;k2<4;k2++)
    pa[k2] = __builtin_bit_cast(bf16x8,
      *(const uint4*)(wsp + P_OFF + ((size_t)(b*64 + ct*4 + w)*4 + k2)*1024 + lane*16));
  float rden[4];
  {
    const float* rg = (const float*)(wsp + RDEN_OFF) + b*1024 + ct*64 + w*16;
    #pragma unroll
    for (int r=0;r<4;r++) rden[r] = rg[l4*4 + r];
  }
  __syncthreads();                             // DMA landed

  f32x4 acc2[8];
  #pragma unroll
  for (int n=0;n<8;n++) acc2[n] = (f32x4){0.f,0.f,0.f,0.f};
  #pragma unroll
  for (int k2=0;k2<4;k2++){
    #pragma unroll
    for (int n=0;n<8;n++){
      bf16x8 bq = __builtin_bit_cast(bf16x8,
        *(const uint4*)(qts + (k2*8 + n)*1024 + lane*16));
      acc2[n] = __builtin_amdgcn_mfma_f32_16x16x32_bf16(pa[k2], bq, acc2[n], 0, 0, 0);
    }
  }

  float* ob = out + (size_t)(b*CC + ct*64 + w*16)*EE + et*128;
  #pragma unroll
  for (int n=0;n<8;n++){
    #pragma unroll
    for (int r=0;r<4;r++)
      ob[(size_t)(l4*4 + r)*EE + n*16 + l15] = acc2[n][r]*rden[r];
  }
}

extern "C" void kernel_launch(void* const* d_in, const int* in_sizes, int n_in,
                              void* d_out, int out_size, void* d_ws, size_t ws_size,
                              hipStream_t stream){
  const float* ctx = (const float*)d_in[0];
  const float* q   = (const float*)d_in[1];
  const float* ws  = (const float*)d_in[2];
  float* out = (float*)d_out;
  unsigned char* wsp = (unsigned char*)d_ws;

  k_prep<<<dim3(BB*4),    dim3(256), 0, stream>>>(q, ws, wsp);
  k_sim <<<dim3(2048),    dim3(512), 0, stream>>>(ctx, wsp);
  k_out <<<dim3(2048+32), dim3(256), 0, stream>>>(wsp, out);
}

// Round 12
// 53.095 us; speedup vs baseline: 1.0299x; 1.0299x over previous
//
#include <hip/hip_runtime.h>

#define BB 32
#define CC 1024
#define QQ 128
#define EE 512

typedef unsigned int uint32;
typedef unsigned short u16;
typedef __bf16 bf16x8 __attribute__((ext_vector_type(8)));
typedef float f32x4 __attribute__((ext_vector_type(4)));

// workspace layout (bytes), total ~21MB
#define QMF_OFF  (0u)                        // bf16 frag-major: [b][ks16][nf8][lane][8] (qm' = q*ws_m + ws_c)
#define QTF_OFF  (4u<<20)                    // bf16 frag-major: [b][ks2 4][ne32][lane][8]
#define QDP_OFF  (8u<<20)                    // f32 [b][et4][128] qdot partials (64KB)
#define MB_OFF   ((8u<<20)+(192u<<10))       // f32 [b][64] tile max (8KB)
#define SB_OFF   ((8u<<20)+(200u<<10))       // f32 [b][64] tile expsum (8KB)
#define PVB_OFF  ((8u<<20)+(256u<<10))       // f32 [b][64][512] q2c partial (4MB)
#define P_OFF    (13u<<20)                   // bf16 P frags (pre-scaled by 1/den): [b][g64][ks2 4][lane][8] (8MB)

__device__ __forceinline__ u16 bfc(float f){
  __bf16 h = (__bf16)f;                // HW v_cvt (RNE)
  return __builtin_bit_cast(u16, h);
}
__device__ __forceinline__ float bf2f(uint32 lo16){
  return __builtin_bit_cast(float, lo16 << 16);
}

// ---- fused prep: per (b, e-slice et): qm' frags + qt frags + qdot partial ----
__global__ __launch_bounds__(256) void k_prep(const float* __restrict__ q,
                                              const float* __restrict__ ws,
                                              unsigned char* __restrict__ wsp){
  const int b = blockIdx.x >> 2, et = blockIdx.x & 3, e0 = et*128;
  __shared__ u16 tm[128*136];          // qm' = q*ws_m + ws_c (bf16)
  __shared__ u16 tt[128*136];          // raw q (bf16)
  const int tid = threadIdx.x;
  float* qdp = (float*)(wsp + QDP_OFF) + (size_t)(b*4 + et)*128;
  #pragma unroll
  for (int i=0;i<16;i++){
    int id = tid + i*256;
    int qi = id >> 5;
    int el = (id & 31) << 2;
    float4 v = *(const float4*)(q + (size_t)(b*QQ+qi)*EE + e0 + el);
    float4 a = *(const float4*)(ws +          e0 + el);
    float4 c = *(const float4*)(ws +   EE +   e0 + el);
    float4 m = *(const float4*)(ws + 2*EE +   e0 + el);
    ushort4 um; um.x = bfc(v.x*m.x + c.x); um.y = bfc(v.y*m.y + c.y);
                um.z = bfc(v.z*m.z + c.z); um.w = bfc(v.w*m.w + c.w);
    *(ushort4*)&tm[qi*136 + el] = um;
    ushort4 ut; ut.x = bfc(v.x); ut.y = bfc(v.y); ut.z = bfc(v.z); ut.w = bfc(v.w);
    *(ushort4*)&tt[qi*136 + el] = ut;
    float d = v.x*a.x + v.y*a.y + v.z*a.z + v.w*a.w;
    d += __shfl_xor(d,1); d += __shfl_xor(d,2); d += __shfl_xor(d,4);
    d += __shfl_xor(d,8); d += __shfl_xor(d,16);
    if ((tid & 31) == 0) qdp[qi] = d;
  }
  __syncthreads();
  const int lane = tid & 63, wv = tid >> 6, l15 = lane & 15, l4 = lane >> 4;
  uint4* qmf = (uint4*)(wsp + QMF_OFF);
  uint4* qtf = (uint4*)(wsp + QTF_OFF);
  #pragma unroll
  for (int i=0;i<8;i++){
    int f = wv*8 + i;
    int kl = f >> 3, nf = f & 7;
    uint4 u = *(const uint4*)&tm[(nf*16 + l15)*136 + kl*32 + l4*8];
    qmf[(size_t)((b*16 + et*4 + kl)*8 + nf)*64 + lane] = u;
  }
  #pragma unroll
  for (int i=0;i<8;i++){
    int f = wv*8 + i;
    int ks2 = f >> 3, nl = f & 7, ne = et*8 + nl;
    uint32 x[4];
    #pragma unroll
    for (int p=0;p<4;p++){
      u16 t0 = tt[(ks2*32 + l4*8 + 2*p    )*136 + nl*16 + l15];
      u16 t1 = tt[(ks2*32 + l4*8 + 2*p + 1)*136 + nl*16 + l15];
      x[p] = (uint32)t0 | ((uint32)t1 << 16);
    }
    uint4 u; u.x = x[0]; u.y = x[1]; u.z = x[2]; u.w = x[3];
    qtf[(size_t)((b*4 + ks2)*32 + ne)*64 + lane] = u;
  }
}

// ---- k_sim: READ-bound. 2048 blocks (b x 16-row tile) x 8 waves.
// ctx tile staged f32 via global_load_lds (linear dest, source slot pre-XOR'd so
// swizzled reads are conflict-free). GEMM1 cvt-on-read; P pre-scaled by 1/den.
__global__ __launch_bounds__(512, 4) void k_sim(const float* __restrict__ ctx,
                                                unsigned char* __restrict__ wsp){
  __shared__ __align__(16) unsigned char buf[32768]; // ctx f32 [16 rows][128 slots of 16B], slot-swizzled
  __shared__ float mx_s[16*8];
  __shared__ float sm_s[16*8];
  __shared__ float wrow_s[16];

  const int bid = blockIdx.x;
  const int sw  = (bid & 7)*256 + (bid >> 3);  // XCD-contiguous (2048%8==0)
  const int b   = sw >> 6;
  const int t   = sw & 63;                     // 16-row tile
  const int tid = threadIdx.x;
  const int lane = tid & 63;
  const int w    = tid >> 6;                   // q-16-group
  const int l15  = lane & 15;
  const int l4   = lane >> 4;

  // stage: 4 global_load_lds per wave, 1KB each. LDS dest linear; global source
  // slot = s ^ (row&7) so LDS(row,s) holds global slot s^(row&7) (involution).
  {
    const unsigned char* cb = (const unsigned char*)(ctx + (size_t)(b*CC + t*16)*EE);
    #pragma unroll
    for (int j=0;j<4;j++){
      const int chunk = w*4 + j;               // 1KB chunk, 0..31
      const int row   = chunk >> 1;
      const int gs    = ((chunk & 1)*64 + lane) ^ (row & 7);
      __builtin_amdgcn_global_load_lds(
        (const __attribute__((address_space(1))) uint32*)(cb + row*2048 + gs*16),
        (__attribute__((address_space(3))) uint32*)(buf + chunk*1024 + lane*16),
        16, 0, 0);
    }
  }

  // qdot (L2-hot, small)
  float qdv[4];
  {
    const float* qdp = (const float*)(wsp + QDP_OFF) + (size_t)b*512;
    #pragma unroll
    for (int r=0;r<4;r++){
      const int qi = w*16 + l4*4 + r;
      qdv[r] = qdp[qi] + qdp[128+qi] + qdp[256+qi] + qdp[384+qi];
    }
  }
  __syncthreads();                             // drains staging DMA (it IS the read phase)

  // GEMM1: sim[q16][c16] = qm'(global frag stream, L2) x ctx(LDS f32 -> bf16)
  const uint4* qmf4 = (const uint4*)(wsp + QMF_OFF);
  f32x4 acc = (f32x4){0.f,0.f,0.f,0.f};
  {
    const int swz = l15 & 7;
    const unsigned char* rowb = buf + l15*2048;
    #pragma unroll
    for (int ks=0; ks<16; ks++){
      bf16x8 a = __builtin_bit_cast(bf16x8, qmf4[(size_t)((b*16 + ks)*8 + w)*64 + lane]);
      const int gs0 = ks*8 + l4*2;
      float4 x = *(const float4*)(rowb + ((gs0    ) ^ swz)*16);
      float4 y = *(const float4*)(rowb + ((gs0 + 1) ^ swz)*16);
      bf16x8 bf;
      bf[0]=(__bf16)x.x; bf[1]=(__bf16)x.y; bf[2]=(__bf16)x.z; bf[3]=(__bf16)x.w;
      bf[4]=(__bf16)y.x; bf[5]=(__bf16)y.y; bf[6]=(__bf16)y.z; bf[7]=(__bf16)y.w;
      acc = __builtin_amdgcn_mfma_f32_16x16x32_bf16(a, bf, acc, 0, 0, 0);
    }
  }

  // softmax (m=0 exp, shift-invariant, clamp 80): raw exps kept in regs; stats -> LDS
  float p[4];
  {
    float m = -3.0e38f, s = 0.f;
    #pragma unroll
    for (int r=0;r<4;r++){
      float vv = fminf(acc[r] + qdv[r], 80.f);
      m = fmaxf(m, vv);
      p[r] = __expf(vv);
      s += p[r];
    }
    m = fmaxf(m, __shfl_xor(m, 16)); m = fmaxf(m, __shfl_xor(m, 32));
    s += __shfl_xor(s, 16);          s += __shfl_xor(s, 32);
    if (l4 == 0){ mx_s[l15*8 + w] = m; sm_s[l15*8 + w] = s; }
  }
  __syncthreads();                             // stats visible

  // rden for this lane's c = l15; write P (pre-scaled) to global
  {
    const float* sp = &sm_s[l15*8];
    const float rden = 1.f/(sp[0]+sp[1]+sp[2]+sp[3]+sp[4]+sp[5]+sp[6]+sp[7]);
    u16 hb[4];
    #pragma unroll
    for (int r=0;r<4;r++) hb[r] = bfc(p[r]*rden);
    uint2 u; u.x = (uint32)hb[0] | ((uint32)hb[1]<<16);
             u.y = (uint32)hb[2] | ((uint32)hb[3]<<16);
    *(uint2*)(wsp + P_OFF
      + ((size_t)(b*64 + t)*4 + (w>>1))*1024
      + (((2*w + (l4>>1)) & 3)*16 + l15)*16 + (l4&1)*8) = u;
  }

  // q2c tile stats (lanes 0..15 of wave 0)
  if (tid < 16){
    const float* mp = &mx_s[tid*8];
    float mf = fmaxf(fmaxf(fmaxf(mp[0],mp[1]),fmaxf(mp[2],mp[3])),
                     fmaxf(fmaxf(mp[4],mp[5]),fmaxf(mp[6],mp[7])));
    float M = mf;
    M = fmaxf(M, __shfl_xor(M,1)); M = fmaxf(M, __shfl_xor(M,2));
    M = fmaxf(M, __shfl_xor(M,4)); M = fmaxf(M, __shfl_xor(M,8));
    float wr = __expf(mf - M);
    wrow_s[tid] = wr;
    float S = wr;
    S += __shfl_xor(S,1); S += __shfl_xor(S,2);
    S += __shfl_xor(S,4); S += __shfl_xor(S,8);
    if (tid == 0){
      ((float*)(wsp + MB_OFF))[b*64 + t] = M;
      ((float*)(wsp + SB_OFF))[b*64 + t] = S;
    }
  }
  __syncthreads();                             // wrow visible

  // q2c PV partial from LDS f32 ctx (thread owns e=tid)
  {
    const int sl = tid >> 2, in = (tid & 3)*4;
    float pv = 0.f;
    #pragma unroll
    for (int rr=0; rr<16; rr++){
      float x = *(const float*)(buf + rr*2048 + ((sl ^ (rr & 7))*16) + in);
      pv = fmaf(wrow_s[rr], x, pv);
    }
    ((float*)(wsp + PVB_OFF))[(size_t)(b*64 + t)*512 + tid] = pv;
  }
}

// ---- k_out: WRITE-bound. 2048 blocks (b x 64-row x 128-e tile) x 4 waves,
// plus 32 fin-blocks (q2c combine). P pre-scaled -> pure load/MFMA/store.
__global__ __launch_bounds__(256, 4) void k_out(unsigned char* __restrict__ wsp,
                                                float* __restrict__ out){
  __shared__ __align__(16) unsigned char qts[32768]; // qtf slice [ks2 4][ne 8][1KB]
  __shared__ float sc_s[64];
  __shared__ float dinv_s;

  const int bid = blockIdx.x;
  const int tid = threadIdx.x;

  if (bid >= 2048){
    // ---- q2c combine for batch b: 64 tile-partials ----
    const int b = bid - 2048;
    if (tid < 64){
      float Mk = ((const float*)(wsp + MB_OFF))[b*64 + tid];
      float Sk = ((const float*)(wsp + SB_OFF))[b*64 + tid];
      float M = Mk;
      M = fmaxf(M, __shfl_xor(M,1));  M = fmaxf(M, __shfl_xor(M,2));
      M = fmaxf(M, __shfl_xor(M,4));  M = fmaxf(M, __shfl_xor(M,8));
      M = fmaxf(M, __shfl_xor(M,16)); M = fmaxf(M, __shfl_xor(M,32));
      float ev = __expf(Mk - M);
      float d = ev*Sk;
      d += __shfl_xor(d,1);  d += __shfl_xor(d,2);  d += __shfl_xor(d,4);
      d += __shfl_xor(d,8);  d += __shfl_xor(d,16); d += __shfl_xor(d,32);
      sc_s[tid] = ev;
      if (tid == 0) dinv_s = 1.f/d;
    }
    __syncthreads();
    const float* pvb = (const float*)(wsp + PVB_OFF) + (size_t)b*64*512;
    float a0 = 0.f, a1 = 0.f;
    #pragma unroll 8
    for (int k=0;k<64;k++){
      float s = sc_s[k];
      a0 = fmaf(s, pvb[(size_t)k*512 + tid],       a0);
      a1 = fmaf(s, pvb[(size_t)k*512 + tid + 256], a1);
    }
    size_t base = (size_t)BB*CC*EE + (size_t)b*EE;
    float di = dinv_s;
    out[base + tid]       = a0*di;
    out[base + tid + 256] = a1*di;
    return;
  }

  const int sw  = (bid & 7)*256 + (bid >> 3);  // XCD-contiguous (2048%8==0)
  const int b   = sw >> 6;
  const int rr  = sw & 63;
  const int ct  = rr >> 2;                     // 64-row tile (0..15)
  const int et  = rr & 3;                      // 128-e tile
  const int lane = tid & 63;
  const int w    = tid >> 6;                   // c-16-group within tile
  const int l15  = lane & 15;
  const int l4   = lane >> 4;

  // DMA qtf slice: wave w loads ks2=w's 8 ne-frags (8KB)
  const unsigned char* qtfb = wsp + QTF_OFF + (size_t)b*131072;
  #pragma unroll
  for (int j=0;j<8;j++){
    __builtin_amdgcn_global_load_lds(
      (const __attribute__((address_space(1))) uint32*)
        (qtfb + (size_t)(w*32 + et*8 + j)*1024 + lane*16),
      (__attribute__((address_space(3))) uint32*)(qts + (w*8 + j)*1024), 16, 0, 0);
  }

  // P A-frags (L3-hot, pre-scaled)
  bf16x8 pa[4];
  #pragma unroll
  for (int k2=0;k2<4;k2++)
    pa[k2] = __builtin_bit_cast(bf16x8,
      *(const uint4*)(wsp + P_OFF + ((size_t)(b*64 + ct*4 + w)*4 + k2)*1024 + lane*16));
  __syncthreads();                             // DMA landed

  f32x4 acc2[8];
  #pragma unroll
  for (int n=0;n<8;n++) acc2[n] = (f32x4){0.f,0.f,0.f,0.f};
  #pragma unroll
  for (int k2=0;k2<4;k2++){
    #pragma unroll
    for (int n=0;n<8;n++){
      bf16x8 bq = __builtin_bit_cast(bf16x8,
        *(const uint4*)(qts + (k2*8 + n)*1024 + lane*16));
      acc2[n] = __builtin_amdgcn_mfma_f32_16x16x32_bf16(pa[k2], bq, acc2[n], 0, 0, 0);
    }
  }

  float* ob = out + (size_t)(b*CC + ct*64 + w*16)*EE + et*128;
  #pragma unroll
  for (int n=0;n<8;n++){
    #pragma unroll
    for (int r=0;r<4;r++)
      ob[(size_t)(l4*4 + r)*EE + n*16 + l15] = acc2[n][r];
  }
}

extern "C" void kernel_launch(void* const* d_in, const int* in_sizes, int n_in,
                              void* d_out, int out_size, void* d_ws, size_t ws_size,
                              hipStream_t stream){
  const float* ctx = (const float*)d_in[0];
  const float* q   = (const float*)d_in[1];
  const float* ws  = (const float*)d_in[2];
  float* out = (float*)d_out;
  unsigned char* wsp = (unsigned char*)d_ws;

  k_prep<<<dim3(BB*4),    dim3(256), 0, stream>>>(q, ws, wsp);
  k_sim <<<dim3(2048),    dim3(512), 0, stream>>>(ctx, wsp);
  k_out <<<dim3(2048+32), dim3(256), 0, stream>>>(wsp, out);
}